// Round 17
// baseline (116.098 us; speedup 1.0000x reference)
//
#include <hip/hip_runtime.h>

#define NB 8
#define NH 512
#define NW 640
#define NHW (NH*NW)
#define TOPK 512
#define PAD 8
#define NBIN2 256        // fine value bins, linear in d = (1.0f bits) - val bits
#define GCAP 4096        // candidate capacity per (source,image)
#define NTILE 160        // tiles per (source,image): 10 x 16
#define TSLOT 256        // list slots owned per tile (>= 242 max survivors)
#define NCHUNK 8
#define TPC 20           // tiles per gather chunk (160/8)

// NMS tile geometry (block = 256 threads)
#define TW 64
#define TH 32
#define INH 36
#define INW 72

// Gaussian taps exp(-2 d^2); |d|>=3 taps are <=1.52e-8 -> negligible, radius 2 used
#define G0 1.0f
#define G1 0.1353352832366127f
#define G2 3.3546262790251185e-4f

// meta layout (u32 indices)
#define M_BINS 0            // 16*256 global fine hists (memset)
#define M_NCAND 4096        // 16 candidate counters (memset)
#define M_TCNT 4112         // 2560 per-tile survivor counts
#define M_DENSE 6672        // 2560: (b*NTILE+t)*2 {f32 bits tsum, u32 vcnt}
#define M_WCNT 9232         // 8
#define M_ACCUM 9240        // 4 u64: [0]=corr fp, [2]=dense f64 bits, [3]=nvis
#define M_DCNT 9248
#define M_ZERO_END 9252     // memset covers [0, M_ZERO_END) u32
#define M_CAND 9256         // 16*GCAP u64 (byte offset %8==0)
#define M_WINNERS 140328    // 8*512 u64 (byte offset %8==0)
#define M_END (M_WINNERS + 8192)

__device__ __forceinline__ float bordered(const float* __restrict__ img, int b, int y, int x) {
  if (y < PAD || y >= NH - PAD || x < PAD || x >= NW - PAD) return 0.f;
  return img[b * NHW + y * NW + x];
}

// Fine bin, monotone NON-INCREASING in val (bin 0 = highest values).
__device__ __forceinline__ int vbin(float val) {
  int d = 0x3F800000 - (int)__float_as_uint(val);
  if (d < 0) d = 0;
  unsigned int bk = (unsigned int)d >> 14;
  return bk > (NBIN2 - 1) ? (NBIN2 - 1) : (int)bk;
}

__device__ __forceinline__ void corner(const float* __restrict__ img, float cx, float cy,
                                       float wgt, float& acc) {
  float valid = (cx >= 0.f && cx <= (float)(NW - 1) && cy >= 0.f && cy <= (float)(NH - 1)) ? 1.f : 0.f;
  float xc = fminf(fmaxf(cx, 0.f), (float)(NW - 1));
  float yc = fminf(fmaxf(cy, 0.f), (float)(NH - 1));
  int xi = (int)xc, yi = (int)yc;
  acc += wgt * img[yi * NW + xi] * valid;
}

// Division-free visibility: v=1 iff x2 in (-1,NW) and y2 in (-1,NH), x2=X/Z.
__device__ __forceinline__ float vis_quad(float h0, float h1, float h2, float h3, float h4,
                                          float h5, float h6, float h7, float h8,
                                          float xf, float yf) {
  float X = h0 * xf + h1 * yf + h2;
  float Y = h3 * xf + h4 * yf + h5;
  float Z = h6 * xf + h7 * yf + h8;
  bool ok = ((X + Z) * Z > 0.f) & ((640.f * Z - X) * Z > 0.f)
          & ((Y + Z) * Z > 0.f) & ((512.f * Z - Y) * Z > 0.f);
  return ok ? 1.f : 0.f;
}

__device__ __forceinline__ void vis_parts(float h0, float h1, float h2, float h3, float h4,
                                          float h5, float h6, float h7, float h8,
                                          float xf, float yf, float L[5]) {
  float X = h0 * xf + h1 * yf + h2;
  float Y = h3 * xf + h4 * yf + h5;
  float Z = h6 * xf + h7 * yf + h8;
  L[0] = X + Z; L[1] = 640.f * Z - X; L[2] = Y + Z; L[3] = 512.f * Z - Y; L[4] = Z;
}

// Fused: one block processes BOTH sources for its tile (all blocks co-resident).
// Tile-owned output slots; per-block conditional atomic flush of 256-bin hist.
__global__ __launch_bounds__(256) void k_nms5(
    const float* __restrict__ score1, const float* __restrict__ score2,
    const float* __restrict__ homo,
    unsigned long long* __restrict__ lists, unsigned int* __restrict__ meta) {
  int bx = blockIdx.x, by = blockIdx.y, b = blockIdx.z;
  int tid = threadIdx.x;
  int t = by * 10 + bx;                 // tile id 0..159

  __shared__ float in[INH][INW];        // 10.1 KB
  __shared__ float hmax[INH][TW];       // 9.0 KB
  __shared__ unsigned int s_cnt;
  __shared__ unsigned int s_bh[NBIN2];  // 1 KB fine hist
  __shared__ float s_wsum[4];
  __shared__ unsigned int s_wcnt[4];

  const float* hm = homo + b * 9;
  float h0 = hm[0], h1 = hm[1], h2 = hm[2];
  float h3 = hm[3], h4 = hm[4], h5 = hm[5];
  float h6 = hm[6], h7 = hm[7], h8 = hm[8];

  int y0t = by * TH, x0t = bx * TW;

  for (int src = 0; src < 2; ++src) {
    if (tid == 0) s_cnt = 0;
    s_bh[tid] = 0;

    // Phase 1: stage tile into LDS (border-filtered values)
    if (src == 0) {
      #pragma unroll
      for (int it = 0; it < 3; ++it) {
        int i = it * 256 + tid;
        if (i < INH * 18) {
          int r = i / 18, c4 = i % 18;
          int gy = y0t + r - 2;
          int gx0 = x0t - 4 + c4 * 4;
          float4 v = make_float4(0.f, 0.f, 0.f, 0.f);
          if (gy >= PAD && gy < NH - PAD) {
            const float4* p = (const float4*)(score1 + (size_t)b * NHW + (size_t)gy * NW + gx0);
            float4 raw = *p;
            v.x = (gx0 + 0 >= PAD && gx0 + 0 < NW - PAD) ? raw.x : 0.f;
            v.y = (gx0 + 1 >= PAD && gx0 + 1 < NW - PAD) ? raw.y : 0.f;
            v.z = (gx0 + 2 >= PAD && gx0 + 2 < NW - PAD) ? raw.z : 0.f;
            v.w = (gx0 + 3 >= PAD && gx0 + 3 < NW - PAD) ? raw.w : 0.f;
          }
          *(float4*)&in[r][c4 * 4] = v;
        }
      }
    } else {
      const float* img = score2 + b * NHW;
      #pragma unroll
      for (int it = 0; it < 10; ++it) {
        int i = it * 256 + tid;
        if (i < INH * 68) {
          int r = i / 68, c = i % 68;
          int gy = y0t + r - 2, gx = x0t - 2 + c;
          float v = 0.f;
          if (gy >= PAD && gy < NH - PAD && gx >= PAD && gx < NW - PAD) {
            float xf = (float)gx, yf = (float)gy;
            float X = h0 * xf + h1 * yf + h2;
            float Y = h3 * xf + h4 * yf + h5;
            float Z = h6 * xf + h7 * yf + h8;
            float rz = __builtin_amdgcn_rcpf(Z);
            float x2 = X * rz, y2 = Y * rz;
            float x0f = floorf(x2), y0f = floorf(y2);
            float x1f = x0f + 1.f, y1f = y0f + 1.f;
            float wa = (x1f - x2) * (y1f - y2);
            float wb = (x2 - x0f) * (y1f - y2);
            float wc = (x1f - x2) * (y2 - y0f);
            float wd = (x2 - x0f) * (y2 - y0f);
            float acc = 0.f;
            if (x0f >= 0.f && x1f <= 639.f && y0f >= 0.f && y1f <= 511.f) {
              const float* p = img + (int)y0f * NW + (int)x0f;
              acc = fmaf(wa, p[0], acc);
              acc = fmaf(wb, p[1], acc);
              acc = fmaf(wc, p[NW], acc);
              acc = fmaf(wd, p[NW + 1], acc);
            } else {
              corner(img, x0f, y0f, wa, acc);
              corner(img, x1f, y0f, wb, acc);
              corner(img, x0f, y1f, wc, acc);
              corner(img, x1f, y1f, wd, acc);
            }
            v = acc;
          }
          in[r][c + 2] = v;
        }
      }
    }
    __syncthreads();

    // Phase 2: horizontal 5-max
    #pragma unroll
    for (int it = 0; it < 9; ++it) {
      int i = it * 256 + tid;
      int r = i >> 6, c = i & 63;
      float m = fmaxf(fmaxf(fmaxf(in[r][c + 2], in[r][c + 3]), fmaxf(in[r][c + 4], in[r][c + 5])),
                      in[r][c + 6]);
      hmax[r][c] = m;
    }
    __syncthreads();

    // src0: block-uniform visibility shortcut
    bool uni = false;
    float vconst = 0.f;
    if (src == 0) {
      float c00[5], c10[5], c01[5], c11[5];
      vis_parts(h0, h1, h2, h3, h4, h5, h6, h7, h8, (float)x0t, (float)y0t, c00);
      vis_parts(h0, h1, h2, h3, h4, h5, h6, h7, h8, (float)(x0t + TW - 1), (float)y0t, c10);
      vis_parts(h0, h1, h2, h3, h4, h5, h6, h7, h8, (float)x0t, (float)(y0t + TH - 1), c01);
      vis_parts(h0, h1, h2, h3, h4, h5, h6, h7, h8, (float)(x0t + TW - 1), (float)(y0t + TH - 1), c11);
      uni = true;
      bool sig[5];
      #pragma unroll
      for (int q = 0; q < 5; ++q) {
        bool allp = (c00[q] > 0.f) & (c10[q] > 0.f) & (c01[q] > 0.f) & (c11[q] > 0.f);
        bool alln = (c00[q] < 0.f) & (c10[q] < 0.f) & (c01[q] < 0.f) & (c11[q] < 0.f);
        uni = uni & (allp | alln);
        sig[q] = allp;
      }
      vconst = (sig[0] == sig[4] && sig[1] == sig[4] && sig[2] == sig[4] && sig[3] == sig[4])
               ? 1.f : 0.f;
    }

    // Phase 3: vertical 5-max + survivor detection (+dense loss terms, src0)
    int nsv = 0;
    float sv[8];
    unsigned int si[8];
    float tsum = 0.f;
    int vcnt = 0;
    #pragma unroll
    for (int it = 0; it < (TH * TW) / 256; ++it) {
      int i = it * 256 + tid;
      int r = i >> 6, c = i & 63;
      int gy = y0t + r, gx = x0t + c;
      float val = in[r + 2][c + 4];
      if (src == 0) {
        float v = uni ? vconst
                      : vis_quad(h0, h1, h2, h3, h4, h5, h6, h7, h8, (float)gx, (float)gy);
        tsum += val * val * v;
        vcnt += (v > 0.f) ? 1 : 0;
      }
      if (val > 0.f) {   // NMS_THRESH = 0
        float m = fmaxf(fmaxf(fmaxf(hmax[r][c], hmax[r + 1][c]), fmaxf(hmax[r + 2][c], hmax[r + 3][c])),
                        hmax[r + 4][c]);
        if (m == val) {
          sv[nsv] = val;
          si[nsv] = (unsigned int)(gy * NW + gx);
          ++nsv;
        }
      }
    }

    // Phase 4: LDS bookkeeping + wave reduce, then readout
    unsigned int local = 0;
    if (nsv > 0) local = atomicAdd(&s_cnt, (unsigned int)nsv);
    #pragma unroll
    for (int j = 0; j < 8; ++j)
      if (j < nsv) atomicAdd(&s_bh[vbin(sv[j])], 1u);

    if (src == 0) {
      for (int m = 1; m < 64; m <<= 1) {
        tsum += __shfl_xor(tsum, m, 64);
        vcnt += __shfl_xor(vcnt, m, 64);
      }
      if ((tid & 63) == 0) { s_wsum[tid >> 6] = tsum; s_wcnt[tid >> 6] = (unsigned int)vcnt; }
    }
    __syncthreads();

    int li = src * NB + b;
    if (tid == 0)
      meta[M_TCNT + li * NTILE + t] = (s_cnt < (unsigned)TSLOT) ? s_cnt : (unsigned)TSLOT;
    // conditional global-atomic hist flush: distinct addresses within a wave
    if (s_bh[tid] > 0)
      atomicAdd(&meta[M_BINS + li * NBIN2 + tid], s_bh[tid]);
    if (src == 0 && tid == 0) {
      float ts = s_wsum[0] + s_wsum[1] + s_wsum[2] + s_wsum[3];
      unsigned int vc = s_wcnt[0] + s_wcnt[1] + s_wcnt[2] + s_wcnt[3];
      meta[M_DENSE + (b * NTILE + t) * 2 + 0] = __float_as_uint(ts);
      meta[M_DENSE + (b * NTILE + t) * 2 + 1] = vc;
    }
    #pragma unroll
    for (int j = 0; j < 8; ++j) {
      if (j < nsv && local + (unsigned)j < (unsigned)TSLOT) {
        unsigned long long key = ((unsigned long long)__float_as_uint(sv[j]) << 32)
                               | (unsigned long long)(~si[j]);
        lists[(size_t)li * (NTILE * TSLOT) + t * TSLOT + local + j] = key;
      }
    }
    __syncthreads();   // before LDS reuse / re-init in next pass
  }
}

// Gather: 128 blocks (16 li x 8 chunks). Each block redundantly computes the
// boundary bin from the global hist (256-entry prefix), then scans 20 tiles'
// slots (5 iterations) pushing candidates to a global compact array.
__global__ __launch_bounds__(1024) void k_gath(
    const unsigned long long* __restrict__ lists, unsigned int* __restrict__ meta) {
  int li = blockIdx.x >> 3;
  int c  = blockIdx.x & 7;
  int tid = threadIdx.x;
  __shared__ unsigned int s_bc[NBIN2];
  __shared__ unsigned int scnt[TPC];
  __shared__ int s_sbb;

  if (tid < NBIN2) s_bc[tid] = meta[M_BINS + li * NBIN2 + tid];
  if (tid < TPC) scnt[tid] = meta[M_TCNT + li * NTILE + c * TPC + tid];
  if (tid == 0) s_sbb = NBIN2 - 1;
  __syncthreads();

  for (int off = 1; off < NBIN2; off <<= 1) {
    unsigned int v = 0;
    if (tid < NBIN2 && tid >= off) v = s_bc[tid - off];
    __syncthreads();
    if (tid < NBIN2) s_bc[tid] += v;
    __syncthreads();
  }
  unsigned int N = s_bc[NBIN2 - 1];
  unsigned int want = (N < TOPK) ? N : TOPK;
  if (tid < NBIN2 && want > 0) {
    unsigned int cum = s_bc[tid];
    unsigned int prev = (tid == 0) ? 0u : s_bc[tid - 1];
    if (cum >= want && prev < want) s_sbb = tid;
  }
  __syncthreads();
  int bb = s_sbb;

  const unsigned long long* list = lists + (size_t)li * (NTILE * TSLOT)
                                         + (size_t)c * (TPC * TSLOT);
  unsigned long long* cand = (unsigned long long*)(meta + M_CAND) + (size_t)li * GCAP;
  int lane = tid & 63;
  #pragma unroll
  for (int it = 0; it < (TPC * TSLOT) / 1024; ++it) {   // 5 iterations
    unsigned int s = it * 1024 + tid;
    unsigned int t = s >> 8, j = s & 255u;
    bool pred = (j < scnt[t]);
    unsigned long long k = 0ULL;
    if (pred) {
      k = list[s];
      float v = __uint_as_float((unsigned int)(k >> 32));
      pred = (vbin(v) <= bb);
    }
    unsigned long long mask = __ballot(pred);
    if (mask) {
      int leader = __ffsll((long long)mask) - 1;
      unsigned int cnt = (unsigned int)__popcll(mask);
      unsigned int bp = 0;
      if (lane == leader) bp = atomicAdd(&meta[M_NCAND + li], cnt);
      bp = __shfl(bp, leader, 64);
      if (pred) {
        unsigned int pos = bp + (unsigned int)__popcll(mask & ((1ULL << lane) - 1ULL));
        if (pos < GCAP) cand[pos] = k;
      }
    }
  }
}

// Rank-select on compact candidates (~600-800): exact top-512 by full 64-bit key.
// src0 -> kp1 out. src1 -> winners rank-sorted by pixel idx asc, written compact.
__global__ __launch_bounds__(1024) void k_rank(
    unsigned int* __restrict__ meta, float* __restrict__ out) {
  int li = blockIdx.x;
  int src = li >> 3, b = li & 7;
  int tid = threadIdx.x;
  __shared__ unsigned long long sbuf[GCAP];
  __shared__ unsigned long long srt[TOPK];

  unsigned int n = meta[M_NCAND + li]; if (n > GCAP) n = GCAP;
  const unsigned long long* cand = (const unsigned long long*)(meta + M_CAND) + (size_t)li * GCAP;
  for (unsigned int i = tid; i < n; i += 1024) sbuf[i] = cand[i];
  __syncthreads();

  for (unsigned int i = tid; i < n; i += 1024) {
    unsigned long long key = sbuf[i];
    unsigned int rank = 0;
    for (unsigned int j = 0; j < n; ++j)
      rank += (sbuf[j] > key) ? 1u : 0u;
    if (rank < TOPK) srt[rank] = key;
  }
  for (unsigned int i = n + tid; i < TOPK; i += 1024) srt[i] = 0ULL;
  __syncthreads();

  if (src == 0) {
    for (int r = tid; r < TOPK; r += 1024) {
      unsigned long long k = srt[r];
      unsigned int idx = (k == 0ULL) ? 0u : ~(unsigned int)(k & 0xFFFFFFFFULL);
      int yy = (int)(idx / NW), xx = (int)(idx % NW);
      out[1 + ((b * TOPK) + r) * 2 + 0] = (float)yy;
      out[1 + ((b * TOPK) + r) * 2 + 1] = (float)xx;
    }
  } else {
    unsigned int nw = (n < TOPK) ? n : TOPK;
    unsigned long long* winners = (unsigned long long*)(meta + M_WINNERS);
    for (unsigned int i = tid; i < nw; i += 1024) {
      unsigned long long k = srt[i];
      unsigned int idx = ~(unsigned int)(k & 0xFFFFFFFFULL);
      unsigned int rank = 0;
      for (unsigned int j = 0; j < nw; ++j) {
        unsigned int idxj = ~(unsigned int)(srt[j] & 0xFFFFFFFFULL);
        rank += (idxj < idx) ? 1u : 0u;
      }
      winners[b * TOPK + rank] = ((unsigned long long)idx << 32) | (k >> 32);
    }
    for (unsigned int i = nw + tid; i < TOPK; i += 1024) winners[b * TOPK + i] = ~0ULL;
    if (tid == 0) meta[M_WCNT + b] = nw;
  }
}

// Sparse gt + correction (gather, owner rule) + final loss.
// Block (0,0) additionally reduces the dense partials (fixed order, f64).
__global__ __launch_bounds__(256) void k_gt2(
    const float* __restrict__ score1, const float* __restrict__ homo,
    unsigned int* __restrict__ meta, float* __restrict__ out) {
  int b = blockIdx.y;
  int tid = threadIdx.x;
  __shared__ unsigned long long w[TOPK];
  __shared__ float s_red[4];
  __shared__ double s_dd[256];
  __shared__ unsigned long long s_cnt64[256];

  unsigned long long* accum = (unsigned long long*)(meta + M_ACCUM);
  const unsigned long long* winners = (const unsigned long long*)(meta + M_WINNERS);
  unsigned int nw = meta[M_WCNT + b];
  for (int i = tid; i < TOPK; i += 256)
    w[i] = (i < (int)nw) ? winners[b * TOPK + i] : ~0ULL;
  __syncthreads();

  const float* hm = homo + b * 9;
  float h0 = hm[0], h1 = hm[1], h2 = hm[2];
  float h3 = hm[3], h4 = hm[4], h5 = hm[5];
  float h6 = hm[6], h7 = hm[7], h8 = hm[8];

  const float gw5[5] = {G2, G1, G0, G1, G2};
  unsigned int r = blockIdx.x * 256u + (unsigned int)tid;
  unsigned int i = r / 25u, k = r % 25u;
  float term = 0.f;
  if (i < nw) {
    unsigned long long wk = w[i];
    unsigned int idx = (unsigned int)(wk >> 32);
    int y = (int)(idx / NW), x = (int)(idx % NW);
    int py = y + (int)(k / 5u) - 2, px = x + (int)(k % 5u) - 2;

    float gt = 0.f;
    unsigned int firstIdx = 0xFFFFFFFFu;
    #pragma unroll
    for (int dr = -2; dr <= 2; ++dr) {
      int ry = py + dr;
      unsigned int lo = (unsigned int)(ry * NW + px - 2);
      unsigned int hi = (unsigned int)(ry * NW + px + 2);
      unsigned long long lokey = ((unsigned long long)lo << 32);
      int a = 0, e = TOPK;
      while (a < e) { int m = (a + e) >> 1; if (w[m] < lokey) a = m + 1; else e = m; }
      for (int j = a; j < TOPK; ++j) {
        unsigned long long c = w[j];
        unsigned int cidx = (unsigned int)(c >> 32);
        if (cidx > hi) break;
        float cval = __uint_as_float((unsigned int)(c & 0xFFFFFFFFULL));
        int cx = (int)(cidx % NW);
        gt += cval * gw5[dr + 2] * gw5[cx - px + 2];
        if (firstIdx == 0xFFFFFFFFu) firstIdx = cidx;
      }
    }
    if (firstIdx == idx) {   // this winner owns pixel p -> exactly-once
      float s1 = bordered(score1, b, py, px);
      float v = vis_quad(h0, h1, h2, h3, h4, h5, h6, h7, h8, (float)px, (float)py);
      term = (gt - 2.f * s1) * gt * v;
    }
  }

  for (int m = 1; m < 64; m <<= 1) term += __shfl_xor(term, m, 64);
  if ((tid & 63) == 0) s_red[tid >> 6] = term;

  if (blockIdx.x == 0 && blockIdx.y == 0) {
    double dsum = 0.0;
    unsigned long long dn = 0;
    for (int i2 = tid; i2 < NB * NTILE; i2 += 256) {
      dsum += (double)__uint_as_float(meta[M_DENSE + 2 * i2]);
      dn += (unsigned long long)meta[M_DENSE + 2 * i2 + 1];
    }
    s_dd[tid] = dsum;
    s_cnt64[tid] = dn;
    __syncthreads();
    for (int s = 128; s > 0; s >>= 1) {
      if (tid < s) { s_dd[tid] += s_dd[tid + s]; s_cnt64[tid] += s_cnt64[tid + s]; }
      __syncthreads();
    }
    if (tid == 0) {
      accum[2] = (unsigned long long)__double_as_longlong(s_dd[0]);
      accum[3] = s_cnt64[0];
    }
  }
  __syncthreads();

  if (tid == 0) {
    float bsum = s_red[0] + s_red[1] + s_red[2] + s_red[3];
    long long fp = (long long)((double)bsum * 4294967296.0);
    atomicAdd(&accum[0], (unsigned long long)fp);
    __threadfence();
    unsigned int old = atomicAdd(meta + M_DCNT, 1u);
    if (old == gridDim.x * gridDim.y - 1u) {
      unsigned long long corr = atomicAdd(&accum[0], 0ULL);
      unsigned long long dbits = atomicAdd(&accum[2], 0ULL);
      unsigned long long nv = atomicAdd(&accum[3], 0ULL);
      double dense = __longlong_as_double((long long)dbits);
      double corrd = (double)(long long)corr / 4294967296.0;
      out[0] = (float)(100.0 * (dense + corrd) / (double)nv);
    }
  }
}

extern "C" void kernel_launch(void* const* d_in, const int* in_sizes, int n_in,
                              void* d_out, int out_size, void* d_ws, size_t ws_size,
                              hipStream_t stream) {
  const float* score1 = (const float*)d_in[0];
  const float* score2 = (const float*)d_in[1];
  const float* homo   = (const float*)d_in[2];
  float* out = (float*)d_out;

  unsigned long long* lists = (unsigned long long*)d_ws;   // 16*160*256 u64 = 5.24 MB
  unsigned int* meta = (unsigned int*)(lists + (size_t)16 * NTILE * TSLOT);

  size_t required = (size_t)16 * NTILE * TSLOT * 8 + (size_t)M_END * 4;
  if (ws_size < required) return;

  hipMemsetAsync(meta, 0, (size_t)M_ZERO_END * 4, stream);

  dim3 gnms(NW / TW, NH / TH, NB);    // 10 x 16 x 8 = 1280 blocks, all co-resident
  k_nms5<<<gnms, 256, 0, stream>>>(score1, score2, homo, lists, meta);
  k_gath<<<128, 1024, 0, stream>>>(lists, meta);
  k_rank<<<16, 1024, 0, stream>>>(meta, out);
  dim3 ggt((TOPK * 25) / 256, NB);    // 50 x 8 = 400 blocks
  k_gt2<<<ggt, 256, 0, stream>>>(score1, homo, meta, out);
}

// Round 18
// 79.950 us; speedup vs baseline: 1.4521x; 1.4521x over previous
//
#include <hip/hip_runtime.h>

#define NB 8
#define NH 512
#define NW 640
#define NHW (NH*NW)
#define TOPK 512
#define PAD 8
#define NBIN2 256        // fine value bins, linear in d = (1.0f bits) - val bits
#define GCAP 4096        // candidate capacity per (source,image)
#define NTILE 160        // tiles per (source,image): 10 x 16
#define TSLOT 256        // list slots owned per tile (>= 242 max survivors)
#define NCHUNK 8
#define TPC 20           // tiles per gather chunk (160/8)

// NMS tile geometry (block = 256 threads)
#define TW 64
#define TH 32
#define INH 36
#define INW 72

// Gaussian taps exp(-2 d^2); |d|>=3 taps are <=1.52e-8 -> negligible, radius 2 used
#define G0 1.0f
#define G1 0.1353352832366127f
#define G2 3.3546262790251185e-4f

// meta layout (u32 indices)
#define M_BINS 0            // 16*256 global fine hists (memset)
#define M_NCAND 4096        // 16 candidate counters (memset)
#define M_TCNT 4112         // 2560 per-tile survivor counts
#define M_DENSE 6672        // 2560: (b*NTILE+t)*2 {f32 bits tsum, u32 vcnt}
#define M_WCNT 9232         // 8
#define M_ACCUM 9240        // 4 u64: [0]=corr fp, [2]=dense f64 bits, [3]=nvis
#define M_DCNT 9248
#define M_ZERO_END 9252     // memset covers [0, M_ZERO_END) u32
#define M_CAND 9256         // 16*GCAP u64 (byte offset %8==0)
#define M_WINNERS 140328    // 8*512 u64 (byte offset %8==0)
#define M_END (M_WINNERS + 8192)

__device__ __forceinline__ float bordered(const float* __restrict__ img, int b, int y, int x) {
  if (y < PAD || y >= NH - PAD || x < PAD || x >= NW - PAD) return 0.f;
  return img[b * NHW + y * NW + x];
}

// Fine bin, monotone NON-INCREASING in val (bin 0 = highest values).
__device__ __forceinline__ int vbin(float val) {
  int d = 0x3F800000 - (int)__float_as_uint(val);
  if (d < 0) d = 0;
  unsigned int bk = (unsigned int)d >> 14;
  return bk > (NBIN2 - 1) ? (NBIN2 - 1) : (int)bk;
}

__device__ __forceinline__ void corner(const float* __restrict__ img, float cx, float cy,
                                       float wgt, float& acc) {
  float valid = (cx >= 0.f && cx <= (float)(NW - 1) && cy >= 0.f && cy <= (float)(NH - 1)) ? 1.f : 0.f;
  float xc = fminf(fmaxf(cx, 0.f), (float)(NW - 1));
  float yc = fminf(fmaxf(cy, 0.f), (float)(NH - 1));
  int xi = (int)xc, yi = (int)yc;
  acc += wgt * img[yi * NW + xi] * valid;
}

// Division-free visibility: v=1 iff x2 in (-1,NW) and y2 in (-1,NH), x2=X/Z.
__device__ __forceinline__ float vis_quad(float h0, float h1, float h2, float h3, float h4,
                                          float h5, float h6, float h7, float h8,
                                          float xf, float yf) {
  float X = h0 * xf + h1 * yf + h2;
  float Y = h3 * xf + h4 * yf + h5;
  float Z = h6 * xf + h7 * yf + h8;
  bool ok = ((X + Z) * Z > 0.f) & ((640.f * Z - X) * Z > 0.f)
          & ((Y + Z) * Z > 0.f) & ((512.f * Z - Y) * Z > 0.f);
  return ok ? 1.f : 0.f;
}

__device__ __forceinline__ void vis_parts(float h0, float h1, float h2, float h3, float h4,
                                          float h5, float h6, float h7, float h8,
                                          float xf, float yf, float L[5]) {
  float X = h0 * xf + h1 * yf + h2;
  float Y = h3 * xf + h4 * yf + h5;
  float Z = h6 * xf + h7 * yf + h8;
  L[0] = X + Z; L[1] = 640.f * Z - X; L[2] = Y + Z; L[3] = 512.f * Z - Y; L[4] = Z;
}

// Fused: one block processes BOTH sources for its tile (all blocks co-resident).
// Tile-owned output slots; per-block conditional atomic flush of 256-bin hist.
__global__ __launch_bounds__(256) void k_nms5(
    const float* __restrict__ score1, const float* __restrict__ score2,
    const float* __restrict__ homo,
    unsigned long long* __restrict__ lists, unsigned int* __restrict__ meta) {
  int bx = blockIdx.x, by = blockIdx.y, b = blockIdx.z;
  int tid = threadIdx.x;
  int t = by * 10 + bx;                 // tile id 0..159

  __shared__ float in[INH][INW];        // 10.1 KB
  __shared__ float hmax[INH][TW];       // 9.0 KB
  __shared__ unsigned int s_cnt;
  __shared__ unsigned int s_bh[NBIN2];  // 1 KB fine hist
  __shared__ float s_wsum[4];
  __shared__ unsigned int s_wcnt[4];

  const float* hm = homo + b * 9;
  float h0 = hm[0], h1 = hm[1], h2 = hm[2];
  float h3 = hm[3], h4 = hm[4], h5 = hm[5];
  float h6 = hm[6], h7 = hm[7], h8 = hm[8];

  int y0t = by * TH, x0t = bx * TW;

  for (int src = 0; src < 2; ++src) {
    if (tid == 0) s_cnt = 0;
    s_bh[tid] = 0;

    // Phase 1: stage tile into LDS (border-filtered values)
    if (src == 0) {
      #pragma unroll
      for (int it = 0; it < 3; ++it) {
        int i = it * 256 + tid;
        if (i < INH * 18) {
          int r = i / 18, c4 = i % 18;
          int gy = y0t + r - 2;
          int gx0 = x0t - 4 + c4 * 4;
          float4 v = make_float4(0.f, 0.f, 0.f, 0.f);
          if (gy >= PAD && gy < NH - PAD) {
            const float4* p = (const float4*)(score1 + (size_t)b * NHW + (size_t)gy * NW + gx0);
            float4 raw = *p;
            v.x = (gx0 + 0 >= PAD && gx0 + 0 < NW - PAD) ? raw.x : 0.f;
            v.y = (gx0 + 1 >= PAD && gx0 + 1 < NW - PAD) ? raw.y : 0.f;
            v.z = (gx0 + 2 >= PAD && gx0 + 2 < NW - PAD) ? raw.z : 0.f;
            v.w = (gx0 + 3 >= PAD && gx0 + 3 < NW - PAD) ? raw.w : 0.f;
          }
          *(float4*)&in[r][c4 * 4] = v;
        }
      }
    } else {
      const float* img = score2 + b * NHW;
      #pragma unroll
      for (int it = 0; it < 10; ++it) {
        int i = it * 256 + tid;
        if (i < INH * 68) {
          int r = i / 68, c = i % 68;
          int gy = y0t + r - 2, gx = x0t - 2 + c;
          float v = 0.f;
          if (gy >= PAD && gy < NH - PAD && gx >= PAD && gx < NW - PAD) {
            float xf = (float)gx, yf = (float)gy;
            float X = h0 * xf + h1 * yf + h2;
            float Y = h3 * xf + h4 * yf + h5;
            float Z = h6 * xf + h7 * yf + h8;
            float rz = __builtin_amdgcn_rcpf(Z);
            float x2 = X * rz, y2 = Y * rz;
            float x0f = floorf(x2), y0f = floorf(y2);
            float x1f = x0f + 1.f, y1f = y0f + 1.f;
            float wa = (x1f - x2) * (y1f - y2);
            float wb = (x2 - x0f) * (y1f - y2);
            float wc = (x1f - x2) * (y2 - y0f);
            float wd = (x2 - x0f) * (y2 - y0f);
            float acc = 0.f;
            if (x0f >= 0.f && x1f <= 639.f && y0f >= 0.f && y1f <= 511.f) {
              const float* p = img + (int)y0f * NW + (int)x0f;
              acc = fmaf(wa, p[0], acc);
              acc = fmaf(wb, p[1], acc);
              acc = fmaf(wc, p[NW], acc);
              acc = fmaf(wd, p[NW + 1], acc);
            } else {
              corner(img, x0f, y0f, wa, acc);
              corner(img, x1f, y0f, wb, acc);
              corner(img, x0f, y1f, wc, acc);
              corner(img, x1f, y1f, wd, acc);
            }
            v = acc;
          }
          in[r][c + 2] = v;
        }
      }
    }
    __syncthreads();

    // Phase 2: horizontal 5-max
    #pragma unroll
    for (int it = 0; it < 9; ++it) {
      int i = it * 256 + tid;
      int r = i >> 6, c = i & 63;
      float m = fmaxf(fmaxf(fmaxf(in[r][c + 2], in[r][c + 3]), fmaxf(in[r][c + 4], in[r][c + 5])),
                      in[r][c + 6]);
      hmax[r][c] = m;
    }
    __syncthreads();

    // src0: block-uniform visibility shortcut
    bool uni = false;
    float vconst = 0.f;
    if (src == 0) {
      float c00[5], c10[5], c01[5], c11[5];
      vis_parts(h0, h1, h2, h3, h4, h5, h6, h7, h8, (float)x0t, (float)y0t, c00);
      vis_parts(h0, h1, h2, h3, h4, h5, h6, h7, h8, (float)(x0t + TW - 1), (float)y0t, c10);
      vis_parts(h0, h1, h2, h3, h4, h5, h6, h7, h8, (float)x0t, (float)(y0t + TH - 1), c01);
      vis_parts(h0, h1, h2, h3, h4, h5, h6, h7, h8, (float)(x0t + TW - 1), (float)(y0t + TH - 1), c11);
      uni = true;
      bool sig[5];
      #pragma unroll
      for (int q = 0; q < 5; ++q) {
        bool allp = (c00[q] > 0.f) & (c10[q] > 0.f) & (c01[q] > 0.f) & (c11[q] > 0.f);
        bool alln = (c00[q] < 0.f) & (c10[q] < 0.f) & (c01[q] < 0.f) & (c11[q] < 0.f);
        uni = uni & (allp | alln);
        sig[q] = allp;
      }
      vconst = (sig[0] == sig[4] && sig[1] == sig[4] && sig[2] == sig[4] && sig[3] == sig[4])
               ? 1.f : 0.f;
    }

    // Phase 3: vertical 5-max + survivor detection (+dense loss terms, src0)
    int nsv = 0;
    float sv[8];
    unsigned int si[8];
    float tsum = 0.f;
    int vcnt = 0;
    #pragma unroll
    for (int it = 0; it < (TH * TW) / 256; ++it) {
      int i = it * 256 + tid;
      int r = i >> 6, c = i & 63;
      int gy = y0t + r, gx = x0t + c;
      float val = in[r + 2][c + 4];
      if (src == 0) {
        float v = uni ? vconst
                      : vis_quad(h0, h1, h2, h3, h4, h5, h6, h7, h8, (float)gx, (float)gy);
        tsum += val * val * v;
        vcnt += (v > 0.f) ? 1 : 0;
      }
      if (val > 0.f) {   // NMS_THRESH = 0
        float m = fmaxf(fmaxf(fmaxf(hmax[r][c], hmax[r + 1][c]), fmaxf(hmax[r + 2][c], hmax[r + 3][c])),
                        hmax[r + 4][c]);
        if (m == val) {
          sv[nsv] = val;
          si[nsv] = (unsigned int)(gy * NW + gx);
          ++nsv;
        }
      }
    }

    // Phase 4: LDS bookkeeping + wave reduce, then readout
    unsigned int local = 0;
    if (nsv > 0) local = atomicAdd(&s_cnt, (unsigned int)nsv);
    #pragma unroll
    for (int j = 0; j < 8; ++j)
      if (j < nsv) atomicAdd(&s_bh[vbin(sv[j])], 1u);

    if (src == 0) {
      for (int m = 1; m < 64; m <<= 1) {
        tsum += __shfl_xor(tsum, m, 64);
        vcnt += __shfl_xor(vcnt, m, 64);
      }
      if ((tid & 63) == 0) { s_wsum[tid >> 6] = tsum; s_wcnt[tid >> 6] = (unsigned int)vcnt; }
    }
    __syncthreads();

    int li = src * NB + b;
    if (tid == 0)
      meta[M_TCNT + li * NTILE + t] = (s_cnt < (unsigned)TSLOT) ? s_cnt : (unsigned)TSLOT;
    // conditional global-atomic hist flush: distinct addresses within a wave
    if (s_bh[tid] > 0)
      atomicAdd(&meta[M_BINS + li * NBIN2 + tid], s_bh[tid]);
    if (src == 0 && tid == 0) {
      float ts = s_wsum[0] + s_wsum[1] + s_wsum[2] + s_wsum[3];
      unsigned int vc = s_wcnt[0] + s_wcnt[1] + s_wcnt[2] + s_wcnt[3];
      meta[M_DENSE + (b * NTILE + t) * 2 + 0] = __float_as_uint(ts);
      meta[M_DENSE + (b * NTILE + t) * 2 + 1] = vc;
    }
    #pragma unroll
    for (int j = 0; j < 8; ++j) {
      if (j < nsv && local + (unsigned)j < (unsigned)TSLOT) {
        unsigned long long key = ((unsigned long long)__float_as_uint(sv[j]) << 32)
                               | (unsigned long long)(~si[j]);
        lists[(size_t)li * (NTILE * TSLOT) + t * TSLOT + local + j] = key;
      }
    }
    __syncthreads();   // before LDS reuse / re-init in next pass
  }
}

// Gather: 128 blocks (16 li x 8 chunks). Boundary bin from global hist, scan 20
// tiles' slots into an LDS buffer (LDS atomics only), then ONE global atomicAdd
// per block reserves the output range, then a coalesced flush.
__global__ __launch_bounds__(1024) void k_gath(
    const unsigned long long* __restrict__ lists, unsigned int* __restrict__ meta) {
  int li = blockIdx.x >> 3;
  int c  = blockIdx.x & 7;
  int tid = threadIdx.x;
  __shared__ unsigned long long buf[GCAP];   // 32 KB block-local candidates
  __shared__ unsigned int s_bc[NBIN2];
  __shared__ unsigned int scnt[TPC];
  __shared__ int s_sbb;
  __shared__ unsigned int s_n, s_base;

  if (tid < NBIN2) s_bc[tid] = meta[M_BINS + li * NBIN2 + tid];
  if (tid < TPC) scnt[tid] = meta[M_TCNT + li * NTILE + c * TPC + tid];
  if (tid == 0) { s_sbb = NBIN2 - 1; s_n = 0; s_base = 0; }
  __syncthreads();

  for (int off = 1; off < NBIN2; off <<= 1) {
    unsigned int v = 0;
    if (tid < NBIN2 && tid >= off) v = s_bc[tid - off];
    __syncthreads();
    if (tid < NBIN2) s_bc[tid] += v;
    __syncthreads();
  }
  unsigned int N = s_bc[NBIN2 - 1];
  unsigned int want = (N < TOPK) ? N : TOPK;
  if (tid < NBIN2 && want > 0) {
    unsigned int cum = s_bc[tid];
    unsigned int prev = (tid == 0) ? 0u : s_bc[tid - 1];
    if (cum >= want && prev < want) s_sbb = tid;
  }
  __syncthreads();
  int bb = s_sbb;

  const unsigned long long* list = lists + (size_t)li * (NTILE * TSLOT)
                                         + (size_t)c * (TPC * TSLOT);
  int lane = tid & 63;
  #pragma unroll
  for (int it = 0; it < (TPC * TSLOT) / 1024; ++it) {   // 5 iterations
    unsigned int s = it * 1024 + tid;
    unsigned int t = s >> 8, j = s & 255u;
    bool pred = (j < scnt[t]);
    unsigned long long k = 0ULL;
    if (pred) {
      k = list[s];
      float v = __uint_as_float((unsigned int)(k >> 32));
      pred = (vbin(v) <= bb);
    }
    unsigned long long mask = __ballot(pred);
    if (mask) {
      int leader = __ffsll((long long)mask) - 1;
      unsigned int cnt = (unsigned int)__popcll(mask);
      unsigned int bp = 0;
      if (lane == leader) bp = atomicAdd(&s_n, cnt);       // LDS atomic only
      bp = __shfl(bp, leader, 64);
      if (pred) {
        unsigned int pos = bp + (unsigned int)__popcll(mask & ((1ULL << lane) - 1ULL));
        if (pos < GCAP) buf[pos] = k;
      }
    }
  }
  __syncthreads();
  unsigned int n = s_n; if (n > GCAP) n = GCAP;
  if (tid == 0 && n > 0) s_base = atomicAdd(&meta[M_NCAND + li], n);  // 1 per block
  __syncthreads();
  unsigned int base = s_base;
  unsigned long long* cand = (unsigned long long*)(meta + M_CAND) + (size_t)li * GCAP;
  for (unsigned int i = tid; i < n; i += 1024) {
    unsigned int pos = base + i;
    if (pos < GCAP) cand[pos] = buf[i];
  }
}

// Rank-select on compact candidates (~600-800): exact top-512 by full 64-bit key.
// src0 -> kp1 out. src1 -> winners rank-sorted by pixel idx asc, written compact.
__global__ __launch_bounds__(1024) void k_rank(
    unsigned int* __restrict__ meta, float* __restrict__ out) {
  int li = blockIdx.x;
  int src = li >> 3, b = li & 7;
  int tid = threadIdx.x;
  __shared__ unsigned long long sbuf[GCAP];
  __shared__ unsigned long long srt[TOPK];

  unsigned int n = meta[M_NCAND + li]; if (n > GCAP) n = GCAP;
  const unsigned long long* cand = (const unsigned long long*)(meta + M_CAND) + (size_t)li * GCAP;
  for (unsigned int i = tid; i < n; i += 1024) sbuf[i] = cand[i];
  __syncthreads();

  for (unsigned int i = tid; i < n; i += 1024) {
    unsigned long long key = sbuf[i];
    unsigned int rank = 0;
    for (unsigned int j = 0; j < n; ++j)
      rank += (sbuf[j] > key) ? 1u : 0u;
    if (rank < TOPK) srt[rank] = key;
  }
  for (unsigned int i = n + tid; i < TOPK; i += 1024) srt[i] = 0ULL;
  __syncthreads();

  if (src == 0) {
    for (int r = tid; r < TOPK; r += 1024) {
      unsigned long long k = srt[r];
      unsigned int idx = (k == 0ULL) ? 0u : ~(unsigned int)(k & 0xFFFFFFFFULL);
      int yy = (int)(idx / NW), xx = (int)(idx % NW);
      out[1 + ((b * TOPK) + r) * 2 + 0] = (float)yy;
      out[1 + ((b * TOPK) + r) * 2 + 1] = (float)xx;
    }
  } else {
    unsigned int nw = (n < TOPK) ? n : TOPK;
    unsigned long long* winners = (unsigned long long*)(meta + M_WINNERS);
    for (unsigned int i = tid; i < nw; i += 1024) {
      unsigned long long k = srt[i];
      unsigned int idx = ~(unsigned int)(k & 0xFFFFFFFFULL);
      unsigned int rank = 0;
      for (unsigned int j = 0; j < nw; ++j) {
        unsigned int idxj = ~(unsigned int)(srt[j] & 0xFFFFFFFFULL);
        rank += (idxj < idx) ? 1u : 0u;
      }
      winners[b * TOPK + rank] = ((unsigned long long)idx << 32) | (k >> 32);
    }
    for (unsigned int i = nw + tid; i < TOPK; i += 1024) winners[b * TOPK + i] = ~0ULL;
    if (tid == 0) meta[M_WCNT + b] = nw;
  }
}

// Sparse gt + correction (gather, owner rule) + final loss.
// Block (0,0) additionally reduces the dense partials (fixed order, f64).
__global__ __launch_bounds__(256) void k_gt2(
    const float* __restrict__ score1, const float* __restrict__ homo,
    unsigned int* __restrict__ meta, float* __restrict__ out) {
  int b = blockIdx.y;
  int tid = threadIdx.x;
  __shared__ unsigned long long w[TOPK];
  __shared__ float s_red[4];
  __shared__ double s_dd[256];
  __shared__ unsigned long long s_cnt64[256];

  unsigned long long* accum = (unsigned long long*)(meta + M_ACCUM);
  const unsigned long long* winners = (const unsigned long long*)(meta + M_WINNERS);
  unsigned int nw = meta[M_WCNT + b];
  for (int i = tid; i < TOPK; i += 256)
    w[i] = (i < (int)nw) ? winners[b * TOPK + i] : ~0ULL;
  __syncthreads();

  const float* hm = homo + b * 9;
  float h0 = hm[0], h1 = hm[1], h2 = hm[2];
  float h3 = hm[3], h4 = hm[4], h5 = hm[5];
  float h6 = hm[6], h7 = hm[7], h8 = hm[8];

  const float gw5[5] = {G2, G1, G0, G1, G2};
  unsigned int r = blockIdx.x * 256u + (unsigned int)tid;
  unsigned int i = r / 25u, k = r % 25u;
  float term = 0.f;
  if (i < nw) {
    unsigned long long wk = w[i];
    unsigned int idx = (unsigned int)(wk >> 32);
    int y = (int)(idx / NW), x = (int)(idx % NW);
    int py = y + (int)(k / 5u) - 2, px = x + (int)(k % 5u) - 2;

    float gt = 0.f;
    unsigned int firstIdx = 0xFFFFFFFFu;
    #pragma unroll
    for (int dr = -2; dr <= 2; ++dr) {
      int ry = py + dr;
      unsigned int lo = (unsigned int)(ry * NW + px - 2);
      unsigned int hi = (unsigned int)(ry * NW + px + 2);
      unsigned long long lokey = ((unsigned long long)lo << 32);
      int a = 0, e = TOPK;
      while (a < e) { int m = (a + e) >> 1; if (w[m] < lokey) a = m + 1; else e = m; }
      for (int j = a; j < TOPK; ++j) {
        unsigned long long c = w[j];
        unsigned int cidx = (unsigned int)(c >> 32);
        if (cidx > hi) break;
        float cval = __uint_as_float((unsigned int)(c & 0xFFFFFFFFULL));
        int cx = (int)(cidx % NW);
        gt += cval * gw5[dr + 2] * gw5[cx - px + 2];
        if (firstIdx == 0xFFFFFFFFu) firstIdx = cidx;
      }
    }
    if (firstIdx == idx) {   // this winner owns pixel p -> exactly-once
      float s1 = bordered(score1, b, py, px);
      float v = vis_quad(h0, h1, h2, h3, h4, h5, h6, h7, h8, (float)px, (float)py);
      term = (gt - 2.f * s1) * gt * v;
    }
  }

  for (int m = 1; m < 64; m <<= 1) term += __shfl_xor(term, m, 64);
  if ((tid & 63) == 0) s_red[tid >> 6] = term;

  if (blockIdx.x == 0 && blockIdx.y == 0) {
    double dsum = 0.0;
    unsigned long long dn = 0;
    for (int i2 = tid; i2 < NB * NTILE; i2 += 256) {
      dsum += (double)__uint_as_float(meta[M_DENSE + 2 * i2]);
      dn += (unsigned long long)meta[M_DENSE + 2 * i2 + 1];
    }
    s_dd[tid] = dsum;
    s_cnt64[tid] = dn;
    __syncthreads();
    for (int s = 128; s > 0; s >>= 1) {
      if (tid < s) { s_dd[tid] += s_dd[tid + s]; s_cnt64[tid] += s_cnt64[tid + s]; }
      __syncthreads();
    }
    if (tid == 0) {
      accum[2] = (unsigned long long)__double_as_longlong(s_dd[0]);
      accum[3] = s_cnt64[0];
    }
  }
  __syncthreads();

  if (tid == 0) {
    float bsum = s_red[0] + s_red[1] + s_red[2] + s_red[3];
    long long fp = (long long)((double)bsum * 4294967296.0);
    atomicAdd(&accum[0], (unsigned long long)fp);
    __threadfence();
    unsigned int old = atomicAdd(meta + M_DCNT, 1u);
    if (old == gridDim.x * gridDim.y - 1u) {
      unsigned long long corr = atomicAdd(&accum[0], 0ULL);
      unsigned long long dbits = atomicAdd(&accum[2], 0ULL);
      unsigned long long nv = atomicAdd(&accum[3], 0ULL);
      double dense = __longlong_as_double((long long)dbits);
      double corrd = (double)(long long)corr / 4294967296.0;
      out[0] = (float)(100.0 * (dense + corrd) / (double)nv);
    }
  }
}

extern "C" void kernel_launch(void* const* d_in, const int* in_sizes, int n_in,
                              void* d_out, int out_size, void* d_ws, size_t ws_size,
                              hipStream_t stream) {
  const float* score1 = (const float*)d_in[0];
  const float* score2 = (const float*)d_in[1];
  const float* homo   = (const float*)d_in[2];
  float* out = (float*)d_out;

  unsigned long long* lists = (unsigned long long*)d_ws;   // 16*160*256 u64 = 5.24 MB
  unsigned int* meta = (unsigned int*)(lists + (size_t)16 * NTILE * TSLOT);

  size_t required = (size_t)16 * NTILE * TSLOT * 8 + (size_t)M_END * 4;
  if (ws_size < required) return;

  hipMemsetAsync(meta, 0, (size_t)M_ZERO_END * 4, stream);

  dim3 gnms(NW / TW, NH / TH, NB);    // 10 x 16 x 8 = 1280 blocks, all co-resident
  k_nms5<<<gnms, 256, 0, stream>>>(score1, score2, homo, lists, meta);
  k_gath<<<128, 1024, 0, stream>>>(lists, meta);
  k_rank<<<16, 1024, 0, stream>>>(meta, out);
  dim3 ggt((TOPK * 25) / 256, NB);    // 50 x 8 = 400 blocks
  k_gt2<<<ggt, 256, 0, stream>>>(score1, homo, meta, out);
}